// Round 2
// baseline (4262.524 us; speedup 1.0000x reference)
//
#include <hip/hip_runtime.h>
#include <hip/hip_bf16.h>

typedef __bf16 bf16_t;
typedef __bf16 bf16x8 __attribute__((ext_vector_type(8)));
typedef float f32x4 __attribute__((ext_vector_type(4)));

#define MFMA16x16x32(a, b, c) __builtin_amdgcn_mfma_f32_16x16x32_bf16((a), (b), (c), 0, 0, 0)

#define B_ 32
#define T_ 64
#define H_ 1024
#define E_ 512
#define V_ 32000
#define H3 3072
#define MROWS 2048  // B*T
#define LOGITS_SZ ((size_t)MROWS * V_)

// ---- cross-XCD coherent access helpers (no fences, so L2 stays warm) ----
// agent-scope relaxed atomic load: forces L2 miss -> always reads fresh data
__device__ __forceinline__ bf16x8 ldx4_agent(const bf16_t* p) {
  const unsigned* q = (const unsigned*)p;
  unsigned a = __hip_atomic_load(q + 0, __ATOMIC_RELAXED, __HIP_MEMORY_SCOPE_AGENT);
  unsigned b = __hip_atomic_load(q + 1, __ATOMIC_RELAXED, __HIP_MEMORY_SCOPE_AGENT);
  unsigned c = __hip_atomic_load(q + 2, __ATOMIC_RELAXED, __HIP_MEMORY_SCOPE_AGENT);
  unsigned d = __hip_atomic_load(q + 3, __ATOMIC_RELAXED, __HIP_MEMORY_SCOPE_AGENT);
  uint4 v = {a, b, c, d};
  return __builtin_bit_cast(bf16x8, v);
}
// agent-scope relaxed atomic store: writes through to coherence point
__device__ __forceinline__ void st_bf16_agent(bf16_t* p, float x) {
  bf16_t h = (bf16_t)x;
  unsigned short u = __builtin_bit_cast(unsigned short, h);
  __hip_atomic_store((unsigned short*)p, u, __ATOMIC_RELAXED, __HIP_MEMORY_SCOPE_AGENT);
}

// ---------------- transpose + fp32->bf16 convert: out[C][R] = (bf16) in[R][C]
__global__ __launch_bounds__(256) void k_transpose_bf16(
    const float* __restrict__ in, bf16_t* __restrict__ out, int R, int C) {
  __shared__ float tile[32][33];
  int c0 = blockIdx.x * 32, r0 = blockIdx.y * 32;
  int tx = threadIdx.x & 31, ty = threadIdx.x >> 5;
#pragma unroll
  for (int i = 0; i < 4; ++i) {
    int r = ty + i * 8;
    tile[r][tx] = in[(size_t)(r0 + r) * C + (c0 + tx)];
  }
  __syncthreads();
#pragma unroll
  for (int i = 0; i < 4; ++i) {
    int r = ty + i * 8;
    out[(size_t)(c0 + r) * R + (r0 + tx)] = (bf16_t)tile[tx][r];
  }
}

// ---------------- build A0 = bf16 [2048][1536] rows: [emb[X[b,t]] | h0[1][b]]
__global__ __launch_bounds__(256) void k_build_A0(
    const int* __restrict__ X, const float* __restrict__ emb,
    const float* __restrict__ h0, bf16_t* __restrict__ A0) {
  int idx = blockIdx.x * 256 + threadIdx.x;  // over 2048*1536
  int row = idx / (E_ + H_);
  int c = idx - row * (E_ + H_);
  float v;
  if (c < E_) {
    int tok = X[row];
    v = emb[(size_t)tok * E_ + c];
  } else {
    int b = row >> 6;  // row = b*T + t
    v = h0[(size_t)B_ * H_ + (size_t)b * H_ + (c - E_)];
  }
  A0[idx] = (bf16_t)v;
}

// ---------------- init hidden-state buffers from h0 (+ reset grid barrier)
__global__ __launch_bounds__(256) void k_init_h(
    const float* __restrict__ h0, float* __restrict__ h1f, bf16_t* __restrict__ h1b,
    float* __restrict__ h2f, bf16_t* __restrict__ h2b, unsigned* __restrict__ bar) {
  int i = blockIdx.x * 256 + threadIdx.x;  // < 32768
  if (i == 0) bar[0] = 0u;
  float a = h0[i], b = h0[B_ * H_ + i];
  h1f[i] = a; h1b[i] = (bf16_t)a;
  h2f[i] = b; h2b[i] = (bf16_t)b;
}

// ---------------- generic bf16 MFMA GEMM: out[M][N] = A[M][K] @ BT[N][K]^T + bias[N]
__global__ __launch_bounds__(256) void k_gemm(
    const bf16_t* __restrict__ A, const bf16_t* __restrict__ BT,
    const float* __restrict__ bias, float* __restrict__ out,
    int M, int N, int K) {
  __shared__ bf16_t Asm[64][40];
  __shared__ bf16_t Bsm[64][40];
  int tid = threadIdx.x;
  int m0 = blockIdx.x * 64, n0 = blockIdx.y * 64;
  int lane = tid & 63, w = tid >> 6;
  int lr = lane & 15, q = lane >> 4;
  int wm = w & 1, wn = w >> 1;
  int srow = tid >> 2, sseg = (tid & 3) * 8;
  f32x4 acc[2][2] = {};
  const bf16_t* Ap = A + (size_t)(m0 + srow) * K + sseg;
  const bf16_t* Bp = BT + (size_t)(n0 + srow) * K + sseg;
  for (int kc = 0; kc < K; kc += 32) {
    *(bf16x8*)&Asm[srow][sseg] = *(const bf16x8*)(Ap + kc);
    *(bf16x8*)&Bsm[srow][sseg] = *(const bf16x8*)(Bp + kc);
    __syncthreads();
#pragma unroll
    for (int sm = 0; sm < 2; ++sm) {
      bf16x8 af = *(const bf16x8*)&Asm[wm * 32 + sm * 16 + lr][q * 8];
#pragma unroll
      for (int sn = 0; sn < 2; ++sn) {
        bf16x8 bfr = *(const bf16x8*)&Bsm[wn * 32 + sn * 16 + lr][q * 8];
        acc[sm][sn] = MFMA16x16x32(af, bfr, acc[sm][sn]);
      }
    }
    __syncthreads();
  }
#pragma unroll
  for (int sm = 0; sm < 2; ++sm)
#pragma unroll
    for (int sn = 0; sn < 2; ++sn) {
      int gr = m0 + wm * 32 + sm * 16 + q * 4;
      int gc = n0 + wn * 32 + sn * 16 + lr;
      float bb = bias[gc];
#pragma unroll
      for (int r = 0; r < 4; ++r)
        out[(size_t)(gr + r) * N + gc] = acc[sm][sn][r] + bb;
    }
}

// ---------------- persistent recurrence kernel, hand-rolled barrier
// 64 blocks x 256 threads. Blocks 0..31: layer0 (t = ph). Blocks 32..63: layer1
// (t = ph - 1). 65 phases. NO cg::grid.sync (its acquire fence invalidates the
// per-XCD L2 every phase -> 41us/phase refetch of 19MB weights from L3; that was
// the entire 2662us). Instead: monotonic agent-scope atomic counter barrier
// (no acquire fence -> weights stay L2-resident) + agent-scope atomic
// loads/stores for the small cross-block h1b/h2b state (always fresh, bypass L2).
struct RecurArgs {
  const bf16_t* U0T;
  const bf16_t* W1T;
  const bf16_t* U1T;
  const float* gx0;
  const float* b0h;  // b0 + H3
  const float* b1x;  // b1
  const float* b1h;  // b1 + H3
  float* h1f0; float* h1f1; float* h2f0; float* h2f1;
  bf16_t* h1b0; bf16_t* h1b1; bf16_t* h2b0; bf16_t* h2b1;
  bf16_t* seqb;
  unsigned* bar;
};

__global__ __launch_bounds__(256) void k_recur(RecurArgs a) {
  const int tid = threadIdx.x, lane = tid & 63, w = tid >> 6;
  const int lr = lane & 15, q = lane >> 4;
  const int blk = blockIdx.x;
  const bool is_l1 = blk >= 32;

  // chunk id within the layer: 0..127  (2 m-tiles x 64 i-groups)
  const int c = (blk & 31) * 4 + w;
  const int wm = c & 1;
  const int ig = c >> 1;
  const int i = ig * 16 + lr;

  // loop-invariant weight row pointers (per-wave slice stays L2-resident)
  const bf16_t* Bz = a.U0T + (size_t)i * H_ + q * 8;
  const bf16_t* Br = Bz + (size_t)H_ * H_;
  const bf16_t* Bh = Br + (size_t)H_ * H_;
  const bf16_t* Wz = a.W1T + (size_t)i * H_ + q * 8;
  const bf16_t* Wr = Wz + (size_t)H_ * H_;
  const bf16_t* Wh = Wr + (size_t)H_ * H_;
  const bf16_t* Uz = a.U1T + (size_t)i * H_ + q * 8;
  const bf16_t* Ur = Uz + (size_t)H_ * H_;
  const bf16_t* Uh = Ur + (size_t)H_ * H_;

  for (int ph = 0; ph < 65; ++ph) {
    if (!is_l1) {
      // ---- layer 0, t = ph: gh = h1 @ U0; gates with precomputed gx0
      int t = ph;
      if (t < 64) {
        int p = t & 1;
        const bf16_t* h1b_c = p ? a.h1b1 : a.h1b0;
        const float*  h1f_c = p ? a.h1f1 : a.h1f0;
        float*  h1f_n = p ? a.h1f0 : a.h1f1;
        bf16_t* h1b_n = p ? a.h1b0 : a.h1b1;
        const bf16_t* Ap = h1b_c + (size_t)(wm * 16 + lr) * H_ + q * 8;
        f32x4 az = {0.f, 0.f, 0.f, 0.f}, ar = {0.f, 0.f, 0.f, 0.f}, ah = {0.f, 0.f, 0.f, 0.f};
#pragma unroll 4
        for (int kc = 0; kc < H_; kc += 32) {
          bf16x8 af = ldx4_agent(Ap + kc);
          az = MFMA16x16x32(af, *(const bf16x8*)(Bz + kc), az);
          ar = MFMA16x16x32(af, *(const bf16x8*)(Br + kc), ar);
          ah = MFMA16x16x32(af, *(const bf16x8*)(Bh + kc), ah);
        }
        float bz = a.b0h[i], br = a.b0h[H_ + i], bhh = a.b0h[2 * H_ + i];
#pragma unroll
        for (int r = 0; r < 4; ++r) {
          int b = wm * 16 + q * 4 + r;
          const float* gx = a.gx0 + (size_t)(b * T_ + t) * H3;
          float z  = 1.f / (1.f + __expf(-(gx[i] + az[r] + bz)));
          float rg = 1.f / (1.f + __expf(-(gx[H_ + i] + ar[r] + br)));
          float hc = tanhf(gx[2 * H_ + i] + rg * (ah[r] + bhh));
          float hold = h1f_c[b * H_ + i];
          float hn = z * hold + (1.f - z) * hc;
          h1f_n[b * H_ + i] = hn;
          st_bf16_agent(&h1b_n[b * H_ + i], hn);
        }
      }
    } else {
      // ---- layer 1, t = ph-1: gx = h1_new @ W1, gh = h2 @ U1
      int t = ph - 1;
      if (t >= 0) {
        int p = t & 1;
        const bf16_t* h1b_new = p ? a.h1b0 : a.h1b1;  // written by layer0 at t
        const bf16_t* h2b_c = p ? a.h2b1 : a.h2b0;
        const float*  h2f_c = p ? a.h2f1 : a.h2f0;
        float*  h2f_n = p ? a.h2f0 : a.h2f1;
        bf16_t* h2b_n = p ? a.h2b0 : a.h2b1;
        const bf16_t* A1 = h1b_new + (size_t)(wm * 16 + lr) * H_ + q * 8;
        const bf16_t* A2 = h2b_c + (size_t)(wm * 16 + lr) * H_ + q * 8;
        f32x4 xz = {0.f, 0.f, 0.f, 0.f}, xr = {0.f, 0.f, 0.f, 0.f}, xh = {0.f, 0.f, 0.f, 0.f};
        f32x4 hz = {0.f, 0.f, 0.f, 0.f}, hr = {0.f, 0.f, 0.f, 0.f}, hh = {0.f, 0.f, 0.f, 0.f};
#pragma unroll 2
        for (int kc = 0; kc < H_; kc += 32) {
          bf16x8 a1 = ldx4_agent(A1 + kc);
          bf16x8 a2 = ldx4_agent(A2 + kc);
          xz = MFMA16x16x32(a1, *(const bf16x8*)(Wz + kc), xz);
          xr = MFMA16x16x32(a1, *(const bf16x8*)(Wr + kc), xr);
          xh = MFMA16x16x32(a1, *(const bf16x8*)(Wh + kc), xh);
          hz = MFMA16x16x32(a2, *(const bf16x8*)(Uz + kc), hz);
          hr = MFMA16x16x32(a2, *(const bf16x8*)(Ur + kc), hr);
          hh = MFMA16x16x32(a2, *(const bf16x8*)(Uh + kc), hh);
        }
        float bxz = a.b1x[i], bxr = a.b1x[H_ + i], bxh = a.b1x[2 * H_ + i];
        float bhz = a.b1h[i], bhr = a.b1h[H_ + i], bhh = a.b1h[2 * H_ + i];
#pragma unroll
        for (int r = 0; r < 4; ++r) {
          int b = wm * 16 + q * 4 + r;
          float z  = 1.f / (1.f + __expf(-(xz[r] + bxz + hz[r] + bhz)));
          float rg = 1.f / (1.f + __expf(-(xr[r] + bxr + hr[r] + bhr)));
          float hc = tanhf(xh[r] + bxh + rg * (hh[r] + bhh));
          float hold = h2f_c[b * H_ + i];
          float hn = z * hold + (1.f - z) * hc;
          h2f_n[b * H_ + i] = hn;
          st_bf16_agent(&h2b_n[b * H_ + i], hn);
          a.seqb[(size_t)(b * T_ + t) * H_ + i] = (bf16_t)hn;
        }
      }
    }
    // ---- grid barrier: monotonic counter, no cache-invalidating fence.
    // __syncthreads drains vmcnt(0) per thread -> all write-through stores of
    // this block are at the coherence point before thread 0 announces arrival.
    if (ph < 64) {
      __syncthreads();
      if (tid == 0) {
        __hip_atomic_fetch_add(a.bar, 1u, __ATOMIC_RELAXED, __HIP_MEMORY_SCOPE_AGENT);
        unsigned target = 64u * (unsigned)(ph + 1);
        while (__hip_atomic_load(a.bar, __ATOMIC_RELAXED, __HIP_MEMORY_SCOPE_AGENT) < target)
          __builtin_amdgcn_s_sleep(2);
      }
      __syncthreads();
    }
  }
}

// ---------------- copy final states to output tail
__global__ __launch_bounds__(256) void k_final(
    const float* __restrict__ h1f, const float* __restrict__ h2f,
    float* __restrict__ out) {
  int i = blockIdx.x * 256 + threadIdx.x;  // < 32768
  out[LOGITS_SZ + i] = h1f[i];
  out[LOGITS_SZ + B_ * H_ + i] = h2f[i];
}

extern "C" void kernel_launch(void* const* d_in, const int* in_sizes, int n_in,
                              void* d_out, int out_size, void* d_ws, size_t ws_size,
                              hipStream_t stream) {
  const int*   X   = (const int*)d_in[0];
  const float* h0  = (const float*)d_in[1];
  const float* emb = (const float*)d_in[2];
  const float* W0  = (const float*)d_in[3];
  const float* U0  = (const float*)d_in[4];
  const float* b0  = (const float*)d_in[5];
  const float* W1  = (const float*)d_in[6];
  const float* U1  = (const float*)d_in[7];
  const float* b1  = (const float*)d_in[8];
  const float* Wd  = (const float*)d_in[9];
  const float* bd  = (const float*)d_in[10];
  float* out = (float*)d_out;

  // workspace layout (~130.3 MB)
  char* p = (char*)d_ws;
  bf16_t* W0T = (bf16_t*)p; p += (size_t)H3 * (E_ + H_) * 2;
  bf16_t* U0T = (bf16_t*)p; p += (size_t)H3 * H_ * 2;
  bf16_t* W1T = (bf16_t*)p; p += (size_t)H3 * H_ * 2;
  bf16_t* U1T = (bf16_t*)p; p += (size_t)H3 * H_ * 2;
  bf16_t* WdT = (bf16_t*)p; p += (size_t)V_ * H_ * 2;
  bf16_t* A0  = (bf16_t*)p; p += (size_t)MROWS * (E_ + H_) * 2;
  bf16_t* seqb = (bf16_t*)p; p += (size_t)MROWS * H_ * 2;
  float* gx0 = (float*)p; p += (size_t)MROWS * H3 * 4;
  float* h1f[2], * h2f[2];
  bf16_t* h1b[2], * h2b[2];
  h1f[0] = (float*)p; p += B_ * H_ * 4;
  h1f[1] = (float*)p; p += B_ * H_ * 4;
  h2f[0] = (float*)p; p += B_ * H_ * 4;
  h2f[1] = (float*)p; p += B_ * H_ * 4;
  h1b[0] = (bf16_t*)p; p += B_ * H_ * 2;
  h1b[1] = (bf16_t*)p; p += B_ * H_ * 2;
  h2b[0] = (bf16_t*)p; p += B_ * H_ * 2;
  h2b[1] = (bf16_t*)p; p += B_ * H_ * 2;
  unsigned* bar = (unsigned*)p; p += 128;

  // weight transposes -> bf16 [N][K]
  k_transpose_bf16<<<dim3(H3 / 32, (E_ + H_) / 32), 256, 0, stream>>>(W0, W0T, E_ + H_, H3);
  k_transpose_bf16<<<dim3(H3 / 32, H_ / 32), 256, 0, stream>>>(U0, U0T, H_, H3);
  k_transpose_bf16<<<dim3(H3 / 32, H_ / 32), 256, 0, stream>>>(W1, W1T, H_, H3);
  k_transpose_bf16<<<dim3(H3 / 32, H_ / 32), 256, 0, stream>>>(U1, U1T, H_, H3);
  k_transpose_bf16<<<dim3(V_ / 32, H_ / 32), 256, 0, stream>>>(Wd, WdT, H_, V_);

  k_build_A0<<<(MROWS * (E_ + H_)) / 256, 256, 0, stream>>>(X, emb, h0, A0);
  k_init_h<<<(B_ * H_) / 256, 256, 0, stream>>>(h0, h1f[0], h1b[0], h2f[0], h2b[0], bar);

  // gx0 = dec_in @ W0 + b0[0]  (all timesteps at once)
  k_gemm<<<dim3(MROWS / 64, H3 / 64), 256, 0, stream>>>(A0, W0T, b0, gx0, MROWS, H3, E_ + H_);

  // sequential recurrence: persistent kernel, 65 pipelined phases, own barrier
  RecurArgs ra;
  ra.U0T = U0T; ra.W1T = W1T; ra.U1T = U1T;
  ra.gx0 = gx0; ra.b0h = b0 + H3; ra.b1x = b1; ra.b1h = b1 + H3;
  ra.h1f0 = h1f[0]; ra.h1f1 = h1f[1]; ra.h2f0 = h2f[0]; ra.h2f1 = h2f[1];
  ra.h1b0 = h1b[0]; ra.h1b1 = h1b[1]; ra.h2b0 = h2b[0]; ra.h2b1 = h2b[1];
  ra.seqb = seqb; ra.bar = bar;
  void* kargs[] = {&ra};
  hipLaunchCooperativeKernel((const void*)k_recur, dim3(64), dim3(256), kargs, 0, stream);

  // logits = seq @ Wd + bd
  k_gemm<<<dim3(MROWS / 64, V_ / 64), 256, 0, stream>>>(seqb, WdT, bd, out, MROWS, V_, H_);

  k_final<<<(B_ * H_) / 256, 256, 0, stream>>>(h1f[0], h2f[0], out);
}

// Round 3
// 1448.117 us; speedup vs baseline: 2.9435x; 2.9435x over previous
//
#include <hip/hip_runtime.h>
#include <hip/hip_bf16.h>

typedef __bf16 bf16_t;
typedef __bf16 bf16x8 __attribute__((ext_vector_type(8)));
typedef float f32x4 __attribute__((ext_vector_type(4)));
typedef unsigned u32x4 __attribute__((ext_vector_type(4)));

#define MFMA16x16x32(a, b, c) __builtin_amdgcn_mfma_f32_16x16x32_bf16((a), (b), (c), 0, 0, 0)

#define B_ 32
#define T_ 64
#define H_ 1024
#define E_ 512
#define V_ 32000
#define H3 3072
#define MROWS 2048  // B*T
#define LOGITS_SZ ((size_t)MROWS * V_)

// ---- batched L2-bypass (agent-coherent) loads: issued back-to-back, drained
// with ONE explicit vmcnt(0). The r2 lesson: __hip_atomic_load in the inner
// loop serializes at ~L3 latency each; inline asm keeps them parallel.
__device__ __forceinline__ u32x4 ld16_sc1(const void* p) {
  u32x4 v;
  asm volatile("global_load_dwordx4 %0, %1, off sc1" : "=v"(v) : "v"(p));
  return v;
}
__device__ __forceinline__ float ldf_sc1(const float* p) {
  float v;
  asm volatile("global_load_dword %0, %1, off sc1" : "=v"(v) : "v"(p));
  return v;
}
// agent-scope relaxed atomic stores: IR-visible, so the s_waitcnt vmcnt(0)
// the compiler emits before s_barrier drains them to the coherence point.
__device__ __forceinline__ void st_bf16_agent(bf16_t* p, float x) {
  bf16_t h = (bf16_t)x;
  unsigned short u = __builtin_bit_cast(unsigned short, h);
  __hip_atomic_store((unsigned short*)p, u, __ATOMIC_RELAXED, __HIP_MEMORY_SCOPE_AGENT);
}
__device__ __forceinline__ void stf_agent(float* p, float x) {
  __hip_atomic_store(p, x, __ATOMIC_RELAXED, __HIP_MEMORY_SCOPE_AGENT);
}

// ---------------- transpose + fp32->bf16 convert: out[C][R] = (bf16) in[R][C]
__global__ __launch_bounds__(256) void k_transpose_bf16(
    const float* __restrict__ in, bf16_t* __restrict__ out, int R, int C) {
  __shared__ float tile[32][33];
  int c0 = blockIdx.x * 32, r0 = blockIdx.y * 32;
  int tx = threadIdx.x & 31, ty = threadIdx.x >> 5;
#pragma unroll
  for (int i = 0; i < 4; ++i) {
    int r = ty + i * 8;
    tile[r][tx] = in[(size_t)(r0 + r) * C + (c0 + tx)];
  }
  __syncthreads();
#pragma unroll
  for (int i = 0; i < 4; ++i) {
    int r = ty + i * 8;
    out[(size_t)(c0 + r) * R + (r0 + tx)] = (bf16_t)tile[tx][r];
  }
}

// ---------------- build A0 = bf16 [2048][1536] rows: [emb[X[b,t]] | h0[1][b]]
__global__ __launch_bounds__(256) void k_build_A0(
    const int* __restrict__ X, const float* __restrict__ emb,
    const float* __restrict__ h0, bf16_t* __restrict__ A0) {
  int idx = blockIdx.x * 256 + threadIdx.x;  // over 2048*1536
  int row = idx / (E_ + H_);
  int c = idx - row * (E_ + H_);
  float v;
  if (c < E_) {
    int tok = X[row];
    v = emb[(size_t)tok * E_ + c];
  } else {
    int b = row >> 6;  // row = b*T + t
    v = h0[(size_t)B_ * H_ + (size_t)b * H_ + (c - E_)];
  }
  A0[idx] = (bf16_t)v;
}

// ---------------- init hidden-state buffers from h0 (+ reset grid barrier)
__global__ __launch_bounds__(256) void k_init_h(
    const float* __restrict__ h0, float* __restrict__ h1f, bf16_t* __restrict__ h1b,
    float* __restrict__ h2f, bf16_t* __restrict__ h2b, unsigned* __restrict__ bar) {
  int i = blockIdx.x * 256 + threadIdx.x;  // < 32768
  if (i == 0) bar[0] = 0u;
  float a = h0[i], b = h0[B_ * H_ + i];
  h1f[i] = a; h1b[i] = (bf16_t)a;
  h2f[i] = b; h2b[i] = (bf16_t)b;
}

// ---------------- generic bf16 MFMA GEMM: out[M][N] = A[M][K] @ BT[N][K]^T + bias[N]
__global__ __launch_bounds__(256) void k_gemm(
    const bf16_t* __restrict__ A, const bf16_t* __restrict__ BT,
    const float* __restrict__ bias, float* __restrict__ out,
    int M, int N, int K) {
  __shared__ bf16_t Asm[64][40];
  __shared__ bf16_t Bsm[64][40];
  int tid = threadIdx.x;
  int m0 = blockIdx.x * 64, n0 = blockIdx.y * 64;
  int lane = tid & 63, w = tid >> 6;
  int lr = lane & 15, q = lane >> 4;
  int wm = w & 1, wn = w >> 1;
  int srow = tid >> 2, sseg = (tid & 3) * 8;
  f32x4 acc[2][2] = {};
  const bf16_t* Ap = A + (size_t)(m0 + srow) * K + sseg;
  const bf16_t* Bp = BT + (size_t)(n0 + srow) * K + sseg;
  for (int kc = 0; kc < K; kc += 32) {
    *(bf16x8*)&Asm[srow][sseg] = *(const bf16x8*)(Ap + kc);
    *(bf16x8*)&Bsm[srow][sseg] = *(const bf16x8*)(Bp + kc);
    __syncthreads();
#pragma unroll
    for (int sm = 0; sm < 2; ++sm) {
      bf16x8 af = *(const bf16x8*)&Asm[wm * 32 + sm * 16 + lr][q * 8];
#pragma unroll
      for (int sn = 0; sn < 2; ++sn) {
        bf16x8 bfr = *(const bf16x8*)&Bsm[wn * 32 + sn * 16 + lr][q * 8];
        acc[sm][sn] = MFMA16x16x32(af, bfr, acc[sm][sn]);
      }
    }
    __syncthreads();
  }
#pragma unroll
  for (int sm = 0; sm < 2; ++sm)
#pragma unroll
    for (int sn = 0; sn < 2; ++sn) {
      int gr = m0 + wm * 32 + sm * 16 + q * 4;
      int gc = n0 + wn * 32 + sn * 16 + lr;
      float bb = bias[gc];
#pragma unroll
      for (int r = 0; r < 4; ++r)
        out[(size_t)(gr + r) * N + gc] = acc[sm][sn][r] + bb;
    }
}

// ---------------- persistent recurrence: weights pinned in LDS
// 192 blocks x 384 threads (6 waves). grp = blk>>6:
//   A (0..63):  h1(t)  = gates(h1(t-1)@U0, gx0[t]),      t = ph
//   B (64..127): gx1(t) = h1(t)@W1 (raw, bias added in C), t = ph-1
//   C (128..191): h2(t) = gates(h2(t-1)@U1, gx1[t]),      t = ph-2
// Per block: LDS = 96KB weight slice (3 gates x 16 cols x K=1024, pinned once)
//          + 64KB hidden-state stage (re-staged each phase via batched sc1 loads).
// Both LDS tiles XOR-granule-swizzled: granule gk stored at gk^(row&7) so
// ds_read_b128/ds_write_b128 are bank-conflict-free.
// Grid barrier: monotonic agent-scope counter, NO acquire fence -> LDS/L1/L2
// state untouched; only the 64KB h-state + 384KB gx1 cross XCDs per phase.
struct RecurArgs {
  const bf16_t *U0T, *W1T, *U1T;
  const float *gx0, *b0h, *b1x, *b1h;
  float *h1f, *h2f, *gx1;
  bf16_t *h1b0, *h1b1, *h2b0, *h2b1, *seqb;
  unsigned* bar;
};

__global__ __launch_bounds__(384) void k_recur(RecurArgs a) {
  extern __shared__ char smem[];
  char* sm_w = smem;            // 98304 B: weights [48 rows][128 granules, swz]
  char* sm_s = smem + 98304;    // 65536 B: stage   [32 rows][128 granules, swz]
  const int tid = threadIdx.x;
  const int lane = tid & 63;
  const int u = tid >> 6;            // wave 0..5
  const int wm = u & 1, g = u >> 1;  // m-tile (batch half), gate (z/r/h)
  const int lr = lane & 15, q = lane >> 4;
  const int blk = blockIdx.x;
  const int grp = blk >> 6;          // 0=A, 1=B, 2=C
  const int ig = blk & 63;
  const int i = ig * 16 + lr;        // output column owned by this lane

  // ---- one-time: pin weight slice into LDS (plain cached loads)
  {
    const bf16_t* wsrc = (grp == 0) ? a.U0T : (grp == 1) ? a.W1T : a.U1T;
    int rr = tid >> 3, c0 = tid & 7;  // rr 0..47
    int wg = rr >> 4, wl = rr & 15;
    const char* srow = (const char*)(wsrc + ((size_t)wg * 1024 + (size_t)ig * 16 + wl) * 1024);
    char* drow = sm_w + (size_t)rr * 2048;
    int sw = rr & 7;
#pragma unroll
    for (int j = 0; j < 16; ++j) {
      int gk = c0 + 8 * j;
      *(u32x4*)(drow + (size_t)((gk ^ sw) * 16)) = *(const u32x4*)(srow + (size_t)gk * 16);
    }
  }
  __syncthreads();

  // hoisted biases (i is fixed per thread)
  float bz = 0.f, br = 0.f, bh3 = 0.f, bxz = 0.f, bxr = 0.f, bxh = 0.f;
  if (grp == 0) { bz = a.b0h[i]; br = a.b0h[H_ + i]; bh3 = a.b0h[2 * H_ + i]; }
  if (grp == 2) {
    bz = a.b1h[i]; br = a.b1h[H_ + i]; bh3 = a.b1h[2 * H_ + i];
    bxz = a.b1x[i]; bxr = a.b1x[H_ + i]; bxh = a.b1x[2 * H_ + i];
  }

  const int swl = lr & 7;
  const char* arow = sm_s + (size_t)(wm * 16 + lr) * 2048;
  const char* wrow = sm_w + (size_t)(g * 16 + lr) * 2048;

  for (int ph = 0; ph < 66; ++ph) {
    int t = (grp == 0) ? ph : (grp == 1) ? (ph - 1) : (ph - 2);
    bool act = (t >= 0) && (t < 64);
    if (act) {
      int par = ph & 1;
      // ---- phase-start loads: stage h-state + early gx loads (latency hidden
      //      under the stage drain + K-loop)
      const bf16_t* hsrc = (grp == 2) ? (par ? a.h2b1 : a.h2b0)
                                      : (par ? a.h1b1 : a.h1b0);
      u32x4 tmp[16];
      float xv0[4], xv1[4], xv2[4];
      if (tid < 256) {
        int sb = tid >> 3, c0 = tid & 7;
        const char* src = (const char*)hsrc + (size_t)sb * 2048 + (size_t)c0 * 16;
#pragma unroll
        for (int j = 0; j < 16; ++j) tmp[j] = ld16_sc1(src + (size_t)j * 128);
      }
      if (grp == 2 && u < 2) {  // C combine waves: gx1(t) written by B last phase
        const float* gxb = a.gx1 + (size_t)(t & 1) * 32 * H3;
#pragma unroll
        for (int r = 0; r < 4; ++r) {
          int b = wm * 16 + q * 4 + r;
          const float* pb = gxb + (size_t)b * H3 + i;
          xv0[r] = ldf_sc1(pb);
          xv1[r] = ldf_sc1(pb + 1024);
          xv2[r] = ldf_sc1(pb + 2048);
        }
      } else if (grp == 0 && u < 2) {  // A combine waves: precomputed gx0 (plain)
#pragma unroll
        for (int r = 0; r < 4; ++r) {
          int b = wm * 16 + q * 4 + r;
          const float* gx = a.gx0 + (size_t)(b * T_ + t) * H3;
          xv0[r] = gx[i]; xv1[r] = gx[H_ + i]; xv2[r] = gx[2 * H_ + i];
        }
      }
      asm volatile("s_waitcnt vmcnt(0)" ::: "memory");
      __builtin_amdgcn_sched_barrier(0);
      if (tid < 256) {
        int sb = tid >> 3, c0 = tid & 7;
        char* dst = sm_s + (size_t)sb * 2048;
        int sw = sb & 7;
#pragma unroll
        for (int j = 0; j < 16; ++j) {
          int gk = c0 + 8 * j;
          *(u32x4*)(dst + (size_t)((gk ^ sw) * 16)) = tmp[j];
        }
      }
      __syncthreads();

      // ---- K-loop: pure LDS. One MFMA chain per wave (m-tile wm, gate g).
      f32x4 acc = {0.f, 0.f, 0.f, 0.f};
#pragma unroll 4
      for (int kc = 0; kc < 32; ++kc) {
        int gi = kc * 4 + q;
        bf16x8 af = *(const bf16x8*)(arow + (size_t)((gi ^ swl) * 16));
        bf16x8 wf = *(const bf16x8*)(wrow + (size_t)((gi ^ swl) * 16));
        acc = MFMA16x16x32(af, wf, acc);
      }

      if (grp == 1) {
        // B: publish raw gx1 slice (agent-visible)
        float* go = a.gx1 + (size_t)(t & 1) * 32 * H3;
#pragma unroll
        for (int r = 0; r < 4; ++r) {
          int b = wm * 16 + q * 4 + r;
          stf_agent(go + (size_t)b * H3 + (size_t)g * 1024 + i, acc[r]);
        }
      } else {
        // A/C: exchange r/h gate pre-acts via LDS scratch (stage area is dead)
        __syncthreads();
        char* scr = sm_s;
        if (g >= 1)
          *(f32x4*)(scr + (size_t)((((g - 1) * 2 + wm) * 64 + lane) * 16)) = acc;
        __syncthreads();
        if (g == 0) {
          f32x4 rgv = *(const f32x4*)(scr + (size_t)(((0 * 2 + wm) * 64 + lane) * 16));
          f32x4 hgv = *(const f32x4*)(scr + (size_t)(((1 * 2 + wm) * 64 + lane) * 16));
          if (grp == 0) {
            bf16_t* h1bn = par ? a.h1b0 : a.h1b1;
#pragma unroll
            for (int r = 0; r < 4; ++r) {
              int b = wm * 16 + q * 4 + r;
              float z  = 1.f / (1.f + __expf(-(xv0[r] + acc[r] + bz)));
              float rg = 1.f / (1.f + __expf(-(xv1[r] + rgv[r] + br)));
              float hc = tanhf(xv2[r] + rg * (hgv[r] + bh3));
              float hold = a.h1f[b * H_ + i];
              float hn = z * hold + (1.f - z) * hc;
              a.h1f[b * H_ + i] = hn;
              st_bf16_agent(&h1bn[b * H_ + i], hn);
            }
          } else {  // grp == 2
            bf16_t* h2bn = par ? a.h2b0 : a.h2b1;
#pragma unroll
            for (int r = 0; r < 4; ++r) {
              int b = wm * 16 + q * 4 + r;
              float z  = 1.f / (1.f + __expf(-(xv0[r] + bxz + acc[r] + bz)));
              float rg = 1.f / (1.f + __expf(-(xv1[r] + bxr + rgv[r] + br)));
              float hc = tanhf(xv2[r] + bxh + rg * (hgv[r] + bh3));
              float hold = a.h2f[b * H_ + i];
              float hn = z * hold + (1.f - z) * hc;
              a.h2f[b * H_ + i] = hn;
              st_bf16_agent(&h2bn[b * H_ + i], hn);
              a.seqb[(size_t)(b * T_ + t) * H_ + i] = (bf16_t)hn;
            }
          }
        }
      }
    }
    // ---- grid barrier: monotonic counter, no cache-invalidating fence.
    if (ph < 65) {
      __syncthreads();  // drains vmcnt(0): all agent stores at coherence point
      if (tid == 0) {
        __hip_atomic_fetch_add(a.bar, 1u, __ATOMIC_RELAXED, __HIP_MEMORY_SCOPE_AGENT);
        unsigned tgt = 192u * (unsigned)(ph + 1);
        while (__hip_atomic_load(a.bar, __ATOMIC_RELAXED, __HIP_MEMORY_SCOPE_AGENT) < tgt)
          __builtin_amdgcn_s_sleep(1);
      }
      __syncthreads();
    }
  }
}

// ---------------- copy final states to output tail
__global__ __launch_bounds__(256) void k_final(
    const float* __restrict__ h1f, const float* __restrict__ h2f,
    float* __restrict__ out) {
  int i = blockIdx.x * 256 + threadIdx.x;  // < 32768
  out[LOGITS_SZ + i] = h1f[i];
  out[LOGITS_SZ + B_ * H_ + i] = h2f[i];
}

extern "C" void kernel_launch(void* const* d_in, const int* in_sizes, int n_in,
                              void* d_out, int out_size, void* d_ws, size_t ws_size,
                              hipStream_t stream) {
  const int*   X   = (const int*)d_in[0];
  const float* h0  = (const float*)d_in[1];
  const float* emb = (const float*)d_in[2];
  const float* W0  = (const float*)d_in[3];
  const float* U0  = (const float*)d_in[4];
  const float* b0  = (const float*)d_in[5];
  const float* W1  = (const float*)d_in[6];
  const float* U1  = (const float*)d_in[7];
  const float* b1  = (const float*)d_in[8];
  const float* Wd  = (const float*)d_in[9];
  const float* bd  = (const float*)d_in[10];
  float* out = (float*)d_out;

  // workspace layout (~130.3 MB), unchanged footprint
  char* p = (char*)d_ws;
  bf16_t* W0T = (bf16_t*)p; p += (size_t)H3 * (E_ + H_) * 2;
  bf16_t* U0T = (bf16_t*)p; p += (size_t)H3 * H_ * 2;
  bf16_t* W1T = (bf16_t*)p; p += (size_t)H3 * H_ * 2;
  bf16_t* U1T = (bf16_t*)p; p += (size_t)H3 * H_ * 2;
  bf16_t* WdT = (bf16_t*)p; p += (size_t)V_ * H_ * 2;
  bf16_t* A0  = (bf16_t*)p; p += (size_t)MROWS * (E_ + H_) * 2;
  bf16_t* seqb = (bf16_t*)p; p += (size_t)MROWS * H_ * 2;
  float* gx0 = (float*)p; p += (size_t)MROWS * H3 * 4;
  float* h1f = (float*)p; p += B_ * H_ * 4;
  float* h1f_unused = (float*)p; p += B_ * H_ * 4;
  float* h2f = (float*)p; p += B_ * H_ * 4;
  float* h2f_unused = (float*)p; p += B_ * H_ * 4;
  bf16_t* h1b0 = (bf16_t*)p; p += B_ * H_ * 2;
  bf16_t* h1b1 = (bf16_t*)p; p += B_ * H_ * 2;
  bf16_t* h2b0 = (bf16_t*)p; p += B_ * H_ * 2;
  bf16_t* h2b1 = (bf16_t*)p; p += B_ * H_ * 2;
  unsigned* bar = (unsigned*)p; p += 128;
  (void)h1f_unused; (void)h2f_unused;
  // gx1 double buffer (2 x 32 x 3072 f32 = 786 KB) aliases A0 (dead after gx0 GEMM)
  float* gx1 = (float*)A0;

  // weight transposes -> bf16 [N][K]
  k_transpose_bf16<<<dim3(H3 / 32, (E_ + H_) / 32), 256, 0, stream>>>(W0, W0T, E_ + H_, H3);
  k_transpose_bf16<<<dim3(H3 / 32, H_ / 32), 256, 0, stream>>>(U0, U0T, H_, H3);
  k_transpose_bf16<<<dim3(H3 / 32, H_ / 32), 256, 0, stream>>>(W1, W1T, H_, H3);
  k_transpose_bf16<<<dim3(H3 / 32, H_ / 32), 256, 0, stream>>>(U1, U1T, H_, H3);
  k_transpose_bf16<<<dim3(V_ / 32, H_ / 32), 256, 0, stream>>>(Wd, WdT, H_, V_);

  k_build_A0<<<(MROWS * (E_ + H_)) / 256, 256, 0, stream>>>(X, emb, h0, A0);
  k_init_h<<<(B_ * H_) / 256, 256, 0, stream>>>(h0, h1f, h1b0, h2f, h2b0, bar);

  // gx0 = dec_in @ W0 + b0[0]  (all timesteps at once)
  k_gemm<<<dim3(MROWS / 64, H3 / 64), 256, 0, stream>>>(A0, W0T, b0, gx0, MROWS, H3, E_ + H_);

  // persistent recurrence: 192 blocks, 160 KB LDS each (opt-in)
  RecurArgs ra;
  ra.U0T = U0T; ra.W1T = W1T; ra.U1T = U1T;
  ra.gx0 = gx0; ra.b0h = b0 + H3; ra.b1x = b1; ra.b1h = b1 + H3;
  ra.h1f = h1f; ra.h2f = h2f; ra.gx1 = gx1;
  ra.h1b0 = h1b0; ra.h1b1 = h1b1; ra.h2b0 = h2b0; ra.h2b1 = h2b1;
  ra.seqb = seqb; ra.bar = bar;
  static int lds_opted = 0;
  if (!lds_opted) {
    hipFuncSetAttribute((const void*)k_recur,
                        hipFuncAttributeMaxDynamicSharedMemorySize, 163840);
    lds_opted = 1;
  }
  void* kargs[] = {&ra};
  hipLaunchCooperativeKernel((const void*)k_recur, dim3(192), dim3(384), kargs,
                             163840, stream);

  // logits = seq @ Wd + bd
  k_gemm<<<dim3(MROWS / 64, V_ / 64), 256, 0, stream>>>(seqb, WdT, bd, out, MROWS, V_, H_);

  k_final<<<(B_ * H_) / 256, 256, 0, stream>>>(h1f, h2f, out);
}

// Round 4
// 1164.003 us; speedup vs baseline: 3.6620x; 1.2441x over previous
//
#include <hip/hip_runtime.h>
#include <hip/hip_bf16.h>

typedef __bf16 bf16_t;
typedef __bf16 bf16x8 __attribute__((ext_vector_type(8)));
typedef float f32x4 __attribute__((ext_vector_type(4)));
typedef unsigned u32x4 __attribute__((ext_vector_type(4)));

#define MFMA16x16x32(a, b, c) __builtin_amdgcn_mfma_f32_16x16x32_bf16((a), (b), (c), 0, 0, 0)

#define B_ 32
#define T_ 64
#define H_ 1024
#define E_ 512
#define V_ 32000
#define H3 3072
#define MROWS 2048  // B*T
#define LOGITS_SZ ((size_t)MROWS * V_)
#define NBLK 192
#define FLAG_STRIDE 16  // uints -> 64B per flag line

// ---- batched L2-bypass (agent-coherent) loads/stores ----
__device__ __forceinline__ u32x4 ld16_sc1(const void* p) {
  u32x4 v;
  asm volatile("global_load_dwordx4 %0, %1, off sc1" : "=v"(v) : "v"(p));
  return v;
}
__device__ __forceinline__ f32x4 ld16f_sc1(const void* p) {
  u32x4 v;
  asm volatile("global_load_dwordx4 %0, %1, off sc1" : "=v"(v) : "v"(p));
  return __builtin_bit_cast(f32x4, v);
}
__device__ __forceinline__ void st16_sc1(void* p, f32x4 v) {
  asm volatile("global_store_dwordx4 %0, %1, off sc1" :: "v"(p), "v"(v) : "memory");
}
__device__ __forceinline__ void st_bf16_agent(bf16_t* p, float x) {
  bf16_t h = (bf16_t)x;
  unsigned short u = __builtin_bit_cast(unsigned short, h);
  __hip_atomic_store((unsigned short*)p, u, __ATOMIC_RELAXED, __HIP_MEMORY_SCOPE_AGENT);
}
__device__ __forceinline__ void st_u32_agent(unsigned* p, unsigned v) {
  __hip_atomic_store(p, v, __ATOMIC_RELAXED, __HIP_MEMORY_SCOPE_AGENT);
}
__device__ __forceinline__ unsigned ld_u32_agent(const unsigned* p) {
  return __hip_atomic_load(p, __ATOMIC_RELAXED, __HIP_MEMORY_SCOPE_AGENT);
}

// async global->LDS, 16B/lane. LDS dest must be wave-uniform; global src per-lane.
__device__ __forceinline__ void gld_lds16(const bf16_t* g, bf16_t* l) {
  __builtin_amdgcn_global_load_lds(
      (const __attribute__((address_space(1))) unsigned*)g,
      (__attribute__((address_space(3))) unsigned*)l, 16, 0, 0);
}

// ---------------- transpose + fp32->bf16 convert: out[C][R] = (bf16) in[R][C]
__global__ __launch_bounds__(256) void k_transpose_bf16(
    const float* __restrict__ in, bf16_t* __restrict__ out, int R, int C) {
  __shared__ float tile[32][33];
  int c0 = blockIdx.x * 32, r0 = blockIdx.y * 32;
  int tx = threadIdx.x & 31, ty = threadIdx.x >> 5;
#pragma unroll
  for (int i = 0; i < 4; ++i) {
    int r = ty + i * 8;
    tile[r][tx] = in[(size_t)(r0 + r) * C + (c0 + tx)];
  }
  __syncthreads();
#pragma unroll
  for (int i = 0; i < 4; ++i) {
    int r = ty + i * 8;
    out[(size_t)(c0 + r) * R + (r0 + tx)] = (bf16_t)tile[tx][r];
  }
}

// ---------------- build A0 = bf16 [2048][1536] rows: [emb[X[b,t]] | h0[1][b]]
__global__ __launch_bounds__(256) void k_build_A0(
    const int* __restrict__ X, const float* __restrict__ emb,
    const float* __restrict__ h0, bf16_t* __restrict__ A0) {
  int idx = blockIdx.x * 256 + threadIdx.x;  // over 2048*1536
  int row = idx / (E_ + H_);
  int c = idx - row * (E_ + H_);
  float v;
  if (c < E_) {
    int tok = X[row];
    v = emb[(size_t)tok * E_ + c];
  } else {
    int b = row >> 6;  // row = b*T + t
    v = h0[(size_t)B_ * H_ + (size_t)b * H_ + (c - E_)];
  }
  A0[idx] = (bf16_t)v;
}

// ---------------- init hidden-state buffers from h0 (+ reset barrier flags)
__global__ __launch_bounds__(256) void k_init_h(
    const float* __restrict__ h0, float* __restrict__ h1f, bf16_t* __restrict__ h1b,
    float* __restrict__ h2f, bf16_t* __restrict__ h2b, unsigned* __restrict__ flags) {
  int i = blockIdx.x * 256 + threadIdx.x;  // < 32768
  if (i < NBLK * FLAG_STRIDE) flags[i] = 0u;  // plain store: kernel-end release flushes L2
  float a = h0[i], b = h0[B_ * H_ + i];
  h1f[i] = a; h1b[i] = (bf16_t)a;
  h2f[i] = b; h2b[i] = (bf16_t)b;
}

// ---------------- bf16 MFMA GEMM, m97 structure: 128x128 tile, 4 waves (2x2),
// each wave 4x4 of 16x16x32 MFMA, linear LDS + global_load_lds width-16 staging.
// out[M][N] = A[M][K] @ BT[N][K]^T + bias[N].  M,N mult of 128; K mult of 32.
__global__ __launch_bounds__(256) void k_gemm(
    const bf16_t* __restrict__ A, const bf16_t* __restrict__ BT,
    const float* __restrict__ bias, float* __restrict__ out,
    int M, int N, int K) {
  __shared__ bf16_t Asm[128 * 32];
  __shared__ bf16_t Bsm[128 * 32];
  int tid = threadIdx.x;
  int m0 = blockIdx.x * 128, n0 = blockIdx.y * 128;
  int lane = tid & 63, w = tid >> 6;
  int lr = lane & 15, q = lane >> 4;
  int wr = w >> 1, wc = w & 1;
  // staging: wave w owns rows [w*32, w*32+32) of both tiles; lane covers
  // (row = w*32 + j*16 + (lane>>2), col8 = (lane&3)*8), two loads j=0,1.
  int srow = lane >> 2, scol = (lane & 3) * 8;
  const bf16_t* Ag = A + (size_t)(m0 + w * 32 + srow) * K + scol;
  const bf16_t* Bg = BT + (size_t)(n0 + w * 32 + srow) * K + scol;
  bf16_t* Ald = Asm + (size_t)(w * 32) * 32;   // wave-uniform LDS bases
  bf16_t* Bld = Bsm + (size_t)(w * 32) * 32;
  f32x4 acc[4][4] = {};
  for (int kc = 0; kc < K; kc += 32) {
    gld_lds16(Ag + kc, Ald);
    gld_lds16(Ag + (size_t)16 * K + kc, Ald + 16 * 32);
    gld_lds16(Bg + kc, Bld);
    gld_lds16(Bg + (size_t)16 * K + kc, Bld + 16 * 32);
    asm volatile("s_waitcnt vmcnt(0)" ::: "memory");
    __syncthreads();
    bf16x8 af[4], bfr[4];
#pragma unroll
    for (int sm = 0; sm < 4; ++sm)
      af[sm] = *(const bf16x8*)&Asm[(size_t)(wr * 64 + sm * 16 + lr) * 32 + q * 8];
#pragma unroll
    for (int sn = 0; sn < 4; ++sn)
      bfr[sn] = *(const bf16x8*)&Bsm[(size_t)(wc * 64 + sn * 16 + lr) * 32 + q * 8];
#pragma unroll
    for (int sm = 0; sm < 4; ++sm)
#pragma unroll
      for (int sn = 0; sn < 4; ++sn)
        acc[sm][sn] = MFMA16x16x32(af[sm], bfr[sn], acc[sm][sn]);
    __syncthreads();
  }
#pragma unroll
  for (int sm = 0; sm < 4; ++sm)
#pragma unroll
    for (int sn = 0; sn < 4; ++sn) {
      int gr = m0 + wr * 64 + sm * 16 + q * 4;
      int gc = n0 + wc * 64 + sn * 16 + lr;
      float bb = bias[gc];
#pragma unroll
      for (int r = 0; r < 4; ++r)
        out[(size_t)(gr + r) * N + gc] = acc[sm][sn][r] + bb;
    }
}

// ---------------- persistent recurrence: weights pinned in LDS (round-3 core)
// Changes vs r3: (1) flag-array barrier (192 x 64B lines, parallel arrival/poll)
// instead of contended fetch_add on one line; (2) gx1 published TRANSPOSED
// [col][b] so B stores and C loads are single dwordx4 sc1 ops.
struct RecurArgs {
  const bf16_t *U0T, *W1T, *U1T;
  const float *gx0, *b0h, *b1x, *b1h;
  float *h1f, *h2f, *gx1t;
  bf16_t *h1b0, *h1b1, *h2b0, *h2b1, *seqb;
  unsigned* flags;
};

__global__ __launch_bounds__(384) void k_recur(RecurArgs a) {
  extern __shared__ char smem[];
  char* sm_w = smem;            // 98304 B: weights [48 rows][128 granules, swz]
  char* sm_s = smem + 98304;    // 65536 B: stage   [32 rows][128 granules, swz]
  const int tid = threadIdx.x;
  const int lane = tid & 63;
  const int u = tid >> 6;            // wave 0..5
  const int wm = u & 1, g = u >> 1;  // m-tile (batch half), gate (z/r/h)
  const int lr = lane & 15, q = lane >> 4;
  const int blk = blockIdx.x;
  const int grp = blk >> 6;          // 0=A(layer0), 1=B(gx1), 2=C(layer1)
  const int ig = blk & 63;
  const int i = ig * 16 + lr;        // output column owned by this lane

  // ---- one-time: pin weight slice into LDS (plain cached loads)
  {
    const bf16_t* wsrc = (grp == 0) ? a.U0T : (grp == 1) ? a.W1T : a.U1T;
    int rr = tid >> 3, c0 = tid & 7;  // rr 0..47
    int wg = rr >> 4, wl = rr & 15;
    const char* srow = (const char*)(wsrc + ((size_t)wg * 1024 + (size_t)ig * 16 + wl) * 1024);
    char* drow = sm_w + (size_t)rr * 2048;
    int sw = rr & 7;
#pragma unroll
    for (int j = 0; j < 16; ++j) {
      int gk = c0 + 8 * j;
      *(u32x4*)(drow + (size_t)((gk ^ sw) * 16)) = *(const u32x4*)(srow + (size_t)gk * 16);
    }
  }
  __syncthreads();

  // hoisted biases (i fixed per thread)
  float bz = 0.f, br = 0.f, bh3 = 0.f, bxz = 0.f, bxr = 0.f, bxh = 0.f;
  if (grp == 0) { bz = a.b0h[i]; br = a.b0h[H_ + i]; bh3 = a.b0h[2 * H_ + i]; }
  if (grp == 2) {
    bz = a.b1h[i]; br = a.b1h[H_ + i]; bh3 = a.b1h[2 * H_ + i];
    bxz = a.b1x[i]; bxr = a.b1x[H_ + i]; bxh = a.b1x[2 * H_ + i];
  }

  const int swl = lr & 7;
  const char* arow = sm_s + (size_t)(wm * 16 + lr) * 2048;
  const char* wrow = sm_w + (size_t)(g * 16 + lr) * 2048;

  for (int ph = 0; ph < 66; ++ph) {
    int t = (grp == 0) ? ph : (grp == 1) ? (ph - 1) : (ph - 2);
    bool act = (t >= 0) && (t < 64);
    if (act) {
      int par = ph & 1;
      const bf16_t* hsrc = (grp == 2) ? (par ? a.h2b1 : a.h2b0)
                                      : (par ? a.h1b1 : a.h1b0);
      u32x4 tmp[16];
      f32x4 xv0, xv1, xv2;
      if (tid < 256) {  // stage full h-state (64KB) via batched sc1 loads
        int sb = tid >> 3, c0 = tid & 7;
        const char* src = (const char*)hsrc + (size_t)sb * 2048 + (size_t)c0 * 16;
#pragma unroll
        for (int j = 0; j < 16; ++j) tmp[j] = ld16_sc1(src + (size_t)j * 128);
      }
      if (grp == 2 && u < 2) {  // C combine waves: gx1t(t) written by B last phase
        const float* gxb = a.gx1t + (size_t)(t & 1) * H3 * 32;
        int boff = wm * 16 + q * 4;
        xv0 = ld16f_sc1(gxb + (size_t)i * 32 + boff);
        xv1 = ld16f_sc1(gxb + (size_t)(1024 + i) * 32 + boff);
        xv2 = ld16f_sc1(gxb + (size_t)(2048 + i) * 32 + boff);
      } else if (grp == 0 && u < 2) {  // A combine waves: precomputed gx0 (plain)
#pragma unroll
        for (int r = 0; r < 4; ++r) {
          int b = wm * 16 + q * 4 + r;
          const float* gx = a.gx0 + (size_t)(b * T_ + t) * H3;
          xv0[r] = gx[i]; xv1[r] = gx[H_ + i]; xv2[r] = gx[2 * H_ + i];
        }
      }
      asm volatile("s_waitcnt vmcnt(0)" ::: "memory");
      __builtin_amdgcn_sched_barrier(0);
      if (tid < 256) {
        int sb = tid >> 3, c0 = tid & 7;
        char* dst = sm_s + (size_t)sb * 2048;
        int sw = sb & 7;
#pragma unroll
        for (int j = 0; j < 16; ++j) {
          int gk = c0 + 8 * j;
          *(u32x4*)(dst + (size_t)((gk ^ sw) * 16)) = tmp[j];
        }
      }
      __syncthreads();

      // ---- K-loop: pure LDS. One MFMA chain per wave (m-tile wm, gate g).
      f32x4 acc = {0.f, 0.f, 0.f, 0.f};
#pragma unroll 4
      for (int kc = 0; kc < 32; ++kc) {
        int gi = kc * 4 + q;
        bf16x8 af = *(const bf16x8*)(arow + (size_t)((gi ^ swl) * 16));
        bf16x8 wf = *(const bf16x8*)(wrow + (size_t)((gi ^ swl) * 16));
        acc = MFMA16x16x32(af, wf, acc);
      }

      if (grp == 1) {
        // B: publish gx1 TRANSPOSED [col][b] -> one dwordx4 per wave-lane
        float* go = a.gx1t + (size_t)(t & 1) * H3 * 32;
        st16_sc1(go + (size_t)(g * 1024 + i) * 32 + wm * 16 + q * 4, acc);
      } else {
        // A/C: exchange r/h gate pre-acts via LDS scratch (stage area is dead)
        __syncthreads();
        char* scr = sm_s;
        if (g >= 1)
          *(f32x4*)(scr + (size_t)((((g - 1) * 2 + wm) * 64 + lane) * 16)) = acc;
        __syncthreads();
        if (g == 0) {
          f32x4 rgv = *(const f32x4*)(scr + (size_t)(((0 * 2 + wm) * 64 + lane) * 16));
          f32x4 hgv = *(const f32x4*)(scr + (size_t)(((1 * 2 + wm) * 64 + lane) * 16));
          if (grp == 0) {
            bf16_t* h1bn = par ? a.h1b0 : a.h1b1;
#pragma unroll
            for (int r = 0; r < 4; ++r) {
              int b = wm * 16 + q * 4 + r;
              float z  = 1.f / (1.f + __expf(-(xv0[r] + acc[r] + bz)));
              float rg = 1.f / (1.f + __expf(-(xv1[r] + rgv[r] + br)));
              float hc = tanhf(xv2[r] + rg * (hgv[r] + bh3));
              float hold = a.h1f[b * H_ + i];
              float hn = z * hold + (1.f - z) * hc;
              a.h1f[b * H_ + i] = hn;
              st_bf16_agent(&h1bn[b * H_ + i], hn);
            }
          } else {  // grp == 2
            bf16_t* h2bn = par ? a.h2b0 : a.h2b1;
#pragma unroll
            for (int r = 0; r < 4; ++r) {
              int b = wm * 16 + q * 4 + r;
              float z  = 1.f / (1.f + __expf(-(xv0[r] + bxz + acc[r] + bz)));
              float rg = 1.f / (1.f + __expf(-(xv1[r] + bxr + rgv[r] + br)));
              float hc = tanhf(xv2[r] + bxh + rg * (hgv[r] + bh3));
              float hold = a.h2f[b * H_ + i];
              float hn = z * hold + (1.f - z) * hc;
              a.h2f[b * H_ + i] = hn;
              st_bf16_agent(&h2bn[b * H_ + i], hn);
              a.seqb[(size_t)(b * T_ + t) * H_ + i] = (bf16_t)hn;
            }
          }
        }
      }
    }
    // ---- flag-array grid barrier: arrival = own write-through flag store;
    // wait = 192 threads each polling one block's flag. No contended atomic,
    // no cache-invalidating fence -> LDS/L2 state untouched.
    if (ph < 65) {
      asm volatile("s_waitcnt vmcnt(0)" ::: "memory");  // drain asm stores too
      __syncthreads();  // all threads' agent stores complete before arrival
      if (tid == 0) st_u32_agent(&a.flags[blk * FLAG_STRIDE], (unsigned)(ph + 1));
      if (tid < NBLK) {
        unsigned tgt = (unsigned)(ph + 1);
        while (ld_u32_agent(&a.flags[tid * FLAG_STRIDE]) < tgt)
          __builtin_amdgcn_s_sleep(2);
      }
      __syncthreads();
    }
  }
}

// ---------------- copy final states to output tail
__global__ __launch_bounds__(256) void k_final(
    const float* __restrict__ h1f, const float* __restrict__ h2f,
    float* __restrict__ out) {
  int i = blockIdx.x * 256 + threadIdx.x;  // < 32768
  out[LOGITS_SZ + i] = h1f[i];
  out[LOGITS_SZ + B_ * H_ + i] = h2f[i];
}

extern "C" void kernel_launch(void* const* d_in, const int* in_sizes, int n_in,
                              void* d_out, int out_size, void* d_ws, size_t ws_size,
                              hipStream_t stream) {
  const int*   X   = (const int*)d_in[0];
  const float* h0  = (const float*)d_in[1];
  const float* emb = (const float*)d_in[2];
  const float* W0  = (const float*)d_in[3];
  const float* U0  = (const float*)d_in[4];
  const float* b0  = (const float*)d_in[5];
  const float* W1  = (const float*)d_in[6];
  const float* U1  = (const float*)d_in[7];
  const float* b1  = (const float*)d_in[8];
  const float* Wd  = (const float*)d_in[9];
  const float* bd  = (const float*)d_in[10];
  float* out = (float*)d_out;

  // workspace layout (~130.3 MB), unchanged footprint
  char* p = (char*)d_ws;
  bf16_t* W0T = (bf16_t*)p; p += (size_t)H3 * (E_ + H_) * 2;
  bf16_t* U0T = (bf16_t*)p; p += (size_t)H3 * H_ * 2;
  bf16_t* W1T = (bf16_t*)p; p += (size_t)H3 * H_ * 2;
  bf16_t* U1T = (bf16_t*)p; p += (size_t)H3 * H_ * 2;
  bf16_t* WdT = (bf16_t*)p; p += (size_t)V_ * H_ * 2;
  bf16_t* A0  = (bf16_t*)p; p += (size_t)MROWS * (E_ + H_) * 2;
  bf16_t* seqb = (bf16_t*)p; p += (size_t)MROWS * H_ * 2;
  float* gx0 = (float*)p; p += (size_t)MROWS * H3 * 4;
  float* h1f = (float*)p; p += B_ * H_ * 4;
  unsigned* flags = (unsigned*)p; p += B_ * H_ * 4;  // reuse dead 128KB slot
  float* h2f = (float*)p; p += B_ * H_ * 4;
  float* h2f_unused = (float*)p; p += B_ * H_ * 4;
  bf16_t* h1b0 = (bf16_t*)p; p += B_ * H_ * 2;
  bf16_t* h1b1 = (bf16_t*)p; p += B_ * H_ * 2;
  bf16_t* h2b0 = (bf16_t*)p; p += B_ * H_ * 2;
  bf16_t* h2b1 = (bf16_t*)p; p += B_ * H_ * 2;
  (void)h2f_unused;
  // gx1t double buffer (2 x 3072 x 32 f32 = 786 KB) aliases A0 (dead after gx0 GEMM)
  float* gx1t = (float*)A0;

  // weight transposes -> bf16 [N][K]
  k_transpose_bf16<<<dim3(H3 / 32, (E_ + H_) / 32), 256, 0, stream>>>(W0, W0T, E_ + H_, H3);
  k_transpose_bf16<<<dim3(H3 / 32, H_ / 32), 256, 0, stream>>>(U0, U0T, H_, H3);
  k_transpose_bf16<<<dim3(H3 / 32, H_ / 32), 256, 0, stream>>>(W1, W1T, H_, H3);
  k_transpose_bf16<<<dim3(H3 / 32, H_ / 32), 256, 0, stream>>>(U1, U1T, H_, H3);
  k_transpose_bf16<<<dim3(V_ / 32, H_ / 32), 256, 0, stream>>>(Wd, WdT, H_, V_);

  k_build_A0<<<(MROWS * (E_ + H_)) / 256, 256, 0, stream>>>(X, emb, h0, A0);
  k_init_h<<<(B_ * H_) / 256, 256, 0, stream>>>(h0, h1f, h1b0, h2f, h2b0, flags);

  // gx0 = dec_in @ W0 + b0[0]  (all timesteps at once)
  k_gemm<<<dim3(MROWS / 128, H3 / 128), 256, 0, stream>>>(A0, W0T, b0, gx0, MROWS, H3, E_ + H_);

  // persistent recurrence: 192 blocks, 160 KB LDS each (opt-in)
  RecurArgs ra;
  ra.U0T = U0T; ra.W1T = W1T; ra.U1T = U1T;
  ra.gx0 = gx0; ra.b0h = b0 + H3; ra.b1x = b1; ra.b1h = b1 + H3;
  ra.h1f = h1f; ra.h2f = h2f; ra.gx1t = gx1t;
  ra.h1b0 = h1b0; ra.h1b1 = h1b1; ra.h2b0 = h2b0; ra.h2b1 = h2b1;
  ra.seqb = seqb; ra.flags = flags;
  static int lds_opted = 0;
  if (!lds_opted) {
    hipFuncSetAttribute((const void*)k_recur,
                        hipFuncAttributeMaxDynamicSharedMemorySize, 163840);
    lds_opted = 1;
  }
  void* kargs[] = {&ra};
  hipLaunchCooperativeKernel((const void*)k_recur, dim3(NBLK), dim3(384), kargs,
                             163840, stream);

  // logits = seq @ Wd + bd
  k_gemm<<<dim3(MROWS / 128, V_ / 128), 256, 0, stream>>>(seqb, WdT, bd, out, MROWS, V_, H_);

  k_final<<<(B_ * H_) / 256, 256, 0, stream>>>(h1f, h2f, out);
}